// Round 5
// baseline (202.197 us; speedup 1.0000x reference)
//
#include <hip/hip_runtime.h>

// Problem constants (fixed by the reference)
#define B_ROWS   512
#define C_COLS   65536
#define BR       4                    // rows per block
#define CCH      8192                 // columns per chunk
#define NCH      (C_COLS / CCH)       // 8 chunks per row
#define RG       (B_ROWS / BR)        // 128 row-groups
#define T1       512                  // threads, kernel 1 (8 waves)
#define ITERS    (CCH / 4 / T1)       // 4 float4 per thread per stream
#define T2       512                  // threads, kernel 2 (== B_ROWS)

// ws layout: [0 .. B_ROWS*NCH) float4 row-chunk partials {num,a2,b2,bce}
//            then NCH floats: per-chunk sum of bce_weights
#define WS_F4_COUNT (B_ROWS * NCH)

__device__ __forceinline__ void wave_reduce4(float& a, float& b, float& c, float& d) {
    #pragma unroll
    for (int off = 32; off >= 1; off >>= 1) {
        a += __shfl_down(a, off);
        b += __shfl_down(b, off);
        c += __shfl_down(c, off);
        d += __shfl_down(d, off);
    }
}

// Kernel 1: each block = 4 rows x one 8192-col chunk.
// Weights loaded once per block serve all 4 rows. VGPR capped for 8 waves/SIMD.
__global__ __launch_bounds__(T1, 8) void coscel_partial(
    const float* __restrict__ pred,
    const float* __restrict__ tgt,
    const float* __restrict__ cw,
    const float* __restrict__ bw,
    float4* __restrict__ ws)
{
    const int blk  = blockIdx.x;          // 0 .. RG*NCH-1 (1024)
    const int rowg = blk / NCH;
    const int ch   = blk % NCH;
    const int tid  = threadIdx.x;

    const int row0 = rowg * BR;
    const size_t cbase = (size_t)ch * CCH;

    const float4* __restrict__ w4 = (const float4*)(cw + cbase);
    const float4* __restrict__ g4 = (const float4*)(bw + cbase);
    const float4* p4[BR];
    const float4* t4[BR];
    #pragma unroll
    for (int r = 0; r < BR; ++r) {
        p4[r] = (const float4*)(pred + (size_t)(row0 + r) * C_COLS + cbase);
        t4[r] = (const float4*)(tgt  + (size_t)(row0 + r) * C_COLS + cbase);
    }

    float num[BR], a2[BR], b2[BR], bce[BR];
    #pragma unroll
    for (int r = 0; r < BR; ++r) { num[r] = a2[r] = b2[r] = bce[r] = 0.f; }
    float gsum = 0.f;

    #pragma unroll 2
    for (int i = 0; i < ITERS; ++i) {
        const int idx = i * T1 + tid;     // coalesced
        const float4 w = w4[idx];
        const float4 g = g4[idx];
        if (rowg == 0)   // block-uniform branch: only chunk-owner blocks need this
            gsum += g.x + g.y + g.z + g.w;

        float4 pv[BR], tv[BR];
        #pragma unroll
        for (int r = 0; r < BR; ++r) { pv[r] = p4[r][idx]; tv[r] = t4[r][idx]; }

        const float4 w2 = make_float4(w.x * w.x, w.y * w.y, w.z * w.z, w.w * w.w);

        #pragma unroll
        for (int r = 0; r < BR; ++r) {
            #define DO_COMP(comp)                                            \
            {                                                                \
                const float x  = tv[r].comp, y = pv[r].comp;                 \
                const float xy = x * y;                                      \
                num[r] = fmaf(xy,    w2.comp, num[r]);                       \
                a2[r]  = fmaf(x * x, w2.comp, a2[r]);                        \
                b2[r]  = fmaf(y * y, w2.comp, b2[r]);                        \
                const float e = __expf(-fabsf(x));                           \
                const float l = __logf(1.0f + e);                            \
                bce[r] += g.comp * (fmaxf(x, 0.0f) - xy + l);                \
            }
            DO_COMP(x) DO_COMP(y) DO_COMP(z) DO_COMP(w)
            #undef DO_COMP
        }
    }

    // Reduce each row's 4 values across the wave (+gsum for rowg==0 blocks).
    #pragma unroll
    for (int r = 0; r < BR; ++r) wave_reduce4(num[r], a2[r], b2[r], bce[r]);
    if (rowg == 0) {
        #pragma unroll
        for (int off = 32; off >= 1; off >>= 1) gsum += __shfl_down(gsum, off);
    }

    __shared__ float4 sred[T1 / 64][BR];
    __shared__ float  sg[T1 / 64];
    const int lane = tid & 63, wid = tid >> 6;
    if (lane == 0) {
        #pragma unroll
        for (int r = 0; r < BR; ++r) sred[wid][r] = make_float4(num[r], a2[r], b2[r], bce[r]);
        sg[wid] = gsum;
    }
    __syncthreads();
    if (tid == 0) {
        #pragma unroll
        for (int r = 0; r < BR; ++r) {
            float4 acc = sred[0][r];
            #pragma unroll
            for (int w_ = 1; w_ < T1 / 64; ++w_) {
                const float4 s = sred[w_][r];
                acc.x += s.x; acc.y += s.y; acc.z += s.z; acc.w += s.w;
            }
            ws[(size_t)(row0 + r) * NCH + ch] = acc;
        }
        if (rowg == 0) {
            float gs = 0.f;
            #pragma unroll
            for (int w_ = 0; w_ < T1 / 64; ++w_) gs += sg[w_];
            ((float*)(ws + WS_F4_COUNT))[ch] = gs;
        }
    }
}

// Kernel 2: fold chunk partials per row, cosine per row, global sums, final scalar.
__global__ __launch_bounds__(T2) void coscel_final(
    const float4* __restrict__ ws,
    float* __restrict__ out)
{
    const int tid = threadIdx.x;    // == row

    float num = 0.f, a2 = 0.f, b2 = 0.f, bce = 0.f;
    #pragma unroll
    for (int c = 0; c < NCH; ++c) {
        const float4 v = ws[(size_t)tid * NCH + c];
        num += v.x; a2 += v.y; b2 += v.z; bce += v.w;
    }
    const float na = fmaxf(sqrtf(a2), 1e-8f);
    const float nb = fmaxf(sqrtf(b2), 1e-8f);
    float cosv = num / (na * nb);

    const float* wpart = (const float*)(ws + WS_F4_COUNT);
    float wsum = (tid < NCH) ? wpart[tid] : 0.f;

    #pragma unroll
    for (int off = 32; off >= 1; off >>= 1) {
        cosv += __shfl_down(cosv, off);
        bce  += __shfl_down(bce,  off);
        wsum += __shfl_down(wsum, off);
    }
    __shared__ float s0[T2 / 64], s1[T2 / 64], s2[T2 / 64];
    const int lane = tid & 63, wid = tid >> 6;
    if (lane == 0) { s0[wid] = cosv; s1[wid] = bce; s2[wid] = wsum; }
    __syncthreads();
    if (tid == 0) {
        float cs = 0.f, bs = 0.f, wss = 0.f;
        #pragma unroll
        for (int i = 0; i < T2 / 64; ++i) { cs += s0[i]; bs += s1[i]; wss += s2[i]; }
        const float cosine_loss = -(cs / (float)B_ROWS);
        const float sub_graph   = bs / (wss + 1e-10f);
        out[0] = cosine_loss + sub_graph / 10.0f;
    }
}

extern "C" void kernel_launch(void* const* d_in, const int* in_sizes, int n_in,
                              void* d_out, int out_size, void* d_ws, size_t ws_size,
                              hipStream_t stream) {
    const float* pred = (const float*)d_in[0];   // prediction (B, C)
    const float* tgt  = (const float*)d_in[1];   // target     (B, C)
    const float* cw   = (const float*)d_in[2];   // cos_weights (C,)
    const float* bw   = (const float*)d_in[3];   // bce_weights (C,)
    float* out = (float*)d_out;
    float4* ws = (float4*)d_ws;                  // 64 KiB partials + 32 B wsum

    coscel_partial<<<RG * NCH, T1, 0, stream>>>(pred, tgt, cw, bw, ws);
    coscel_final<<<1, T2, 0, stream>>>(ws, out);
}

// Round 6
// 76.091 us; speedup vs baseline: 2.6573x; 2.6573x over previous
//
#include <hip/hip_runtime.h>

// Problem constants (fixed by the reference)
#define B_ROWS   512
#define C_COLS   65536
#define BR       4                    // rows per block
#define CCH      4096                 // columns per chunk
#define NCH      (C_COLS / CCH)       // 16 chunks per row
#define RG       (B_ROWS / BR)        // 128 row-groups
#define NBLK     (RG * NCH)           // 2048 blocks
#define T1       256                  // threads
#define ITERS    (CCH / 4 / T1)       // 4 float4 per thread per stream

// ws layout:
//   [0, 128 KiB)   : float part[B_ROWS][NCH][4]  {num, a2, b2, bce}
//   [128K, +64B)   : float wsum[NCH]             per-chunk sum of bce_weights
//   [128K + 128B]  : uint counter                (zeroed by memset node each launch)
#define WS_WSUM_OFF  (B_ROWS * NCH * 16)          // bytes
#define WS_CTR_OFF   (WS_WSUM_OFF + 128)          // bytes

__device__ __forceinline__ void wave_reduce4(float& a, float& b, float& c, float& d) {
    #pragma unroll
    for (int off = 32; off >= 1; off >>= 1) {
        a += __shfl_down(a, off);
        b += __shfl_down(b, off);
        c += __shfl_down(c, off);
        d += __shfl_down(d, off);
    }
}

// Agent-scope (device) coherent store/load: write-through past the XCD L2,
// read bypassing the XCD L2. No cache-maintenance fences anywhere.
__device__ __forceinline__ void coh_store(float* p, float v) {
    __hip_atomic_store((unsigned int*)p, __builtin_bit_cast(unsigned int, v),
                       __ATOMIC_RELAXED, __HIP_MEMORY_SCOPE_AGENT);
}
__device__ __forceinline__ float coh_load(const float* p) {
    unsigned int u = __hip_atomic_load((const unsigned int*)p,
                                       __ATOMIC_RELAXED, __HIP_MEMORY_SCOPE_AGENT);
    return __builtin_bit_cast(float, u);
}

__global__ __launch_bounds__(T1) void coscel_fused(
    const float* __restrict__ pred,
    const float* __restrict__ tgt,
    const float* __restrict__ cw,
    const float* __restrict__ bw,
    float* __restrict__ part,          // [B_ROWS][NCH][4]
    float* __restrict__ wsum,          // [NCH]
    unsigned int* __restrict__ counter,
    float* __restrict__ out)
{
    const int blk  = blockIdx.x;          // 0 .. NBLK-1
    const int rowg = blk / NCH;
    const int ch   = blk % NCH;
    const int tid  = threadIdx.x;

    const int row0 = rowg * BR;
    const size_t cbase = (size_t)ch * CCH;

    const float4* __restrict__ w4 = (const float4*)(cw + cbase);
    const float4* __restrict__ g4 = (const float4*)(bw + cbase);
    const float4* p4[BR];
    const float4* t4[BR];
    #pragma unroll
    for (int r = 0; r < BR; ++r) {
        p4[r] = (const float4*)(pred + (size_t)(row0 + r) * C_COLS + cbase);
        t4[r] = (const float4*)(tgt  + (size_t)(row0 + r) * C_COLS + cbase);
    }

    float num[BR], a2[BR], b2[BR], bce[BR];
    #pragma unroll
    for (int r = 0; r < BR; ++r) { num[r] = a2[r] = b2[r] = bce[r] = 0.f; }
    float gsum = 0.f;

    #pragma unroll 2
    for (int i = 0; i < ITERS; ++i) {
        const int idx = i * T1 + tid;     // coalesced
        const float4 w = w4[idx];
        const float4 g = g4[idx];
        gsum += g.x + g.y + g.z + g.w;

        float4 pv[BR], tv[BR];
        #pragma unroll
        for (int r = 0; r < BR; ++r) { pv[r] = p4[r][idx]; tv[r] = t4[r][idx]; }

        const float4 w2 = make_float4(w.x * w.x, w.y * w.y, w.z * w.z, w.w * w.w);

        #pragma unroll
        for (int r = 0; r < BR; ++r) {
            #define DO_COMP(comp)                                            \
            {                                                                \
                const float x  = tv[r].comp, y = pv[r].comp;                 \
                const float xy = x * y;                                      \
                num[r] = fmaf(xy,    w2.comp, num[r]);                       \
                a2[r]  = fmaf(x * x, w2.comp, a2[r]);                        \
                b2[r]  = fmaf(y * y, w2.comp, b2[r]);                        \
                const float e = __expf(-fabsf(x));                           \
                const float l = __logf(1.0f + e);                            \
                bce[r] += g.comp * (fmaxf(x, 0.0f) - xy + l);                \
            }
            DO_COMP(x) DO_COMP(y) DO_COMP(z) DO_COMP(w)
            #undef DO_COMP
        }
    }

    // Per-wave reduce, then cross-wave via LDS.
    #pragma unroll
    for (int r = 0; r < BR; ++r) wave_reduce4(num[r], a2[r], b2[r], bce[r]);
    #pragma unroll
    for (int off = 32; off >= 1; off >>= 1) gsum += __shfl_down(gsum, off);

    __shared__ float4 sred[T1 / 64][BR];
    __shared__ float  sg[T1 / 64];
    __shared__ int    slast;
    const int lane = tid & 63, wid = tid >> 6;
    if (lane == 0) {
        #pragma unroll
        for (int r = 0; r < BR; ++r) sred[wid][r] = make_float4(num[r], a2[r], b2[r], bce[r]);
        sg[wid] = gsum;
    }
    __syncthreads();

    if (tid == 0) {
        // Publish partials via coherent (sc1) stores — visible device-wide
        // once vmcnt drains; no L2 writeback/invalidate needed.
        #pragma unroll
        for (int r = 0; r < BR; ++r) {
            float4 acc = sred[0][r];
            #pragma unroll
            for (int w_ = 1; w_ < T1 / 64; ++w_) {
                const float4 s = sred[w_][r];
                acc.x += s.x; acc.y += s.y; acc.z += s.z; acc.w += s.w;
            }
            float* dst = part + ((size_t)(row0 + r) * NCH + ch) * 4;
            coh_store(dst + 0, acc.x);
            coh_store(dst + 1, acc.y);
            coh_store(dst + 2, acc.z);
            coh_store(dst + 3, acc.w);
        }
        if (rowg == 0) {
            coh_store(&wsum[ch], sg[0] + sg[1] + sg[2] + sg[3]);
        }
        // Order the publishes before the arrival increment: wave-local drain.
        asm volatile("s_waitcnt vmcnt(0)" ::: "memory");
        const unsigned int old = __hip_atomic_fetch_add(
            counter, 1u, __ATOMIC_RELAXED, __HIP_MEMORY_SCOPE_AGENT);
        slast = (old == (unsigned int)(NBLK - 1));
    }
    __syncthreads();
    if (!slast) return;

    // ---- Finisher: the last-arriving block folds everything. ----
    // Fixed slots summed in fixed order -> bitwise deterministic output.
    float cos_acc = 0.f, bce_acc = 0.f;
    #pragma unroll
    for (int rr = 0; rr < B_ROWS / T1; ++rr) {
        const int r = rr * T1 + tid;
        float n = 0.f, aa = 0.f, bb = 0.f, bc = 0.f;
        #pragma unroll
        for (int c = 0; c < NCH; ++c) {
            const float* src = part + ((size_t)r * NCH + c) * 4;
            n  += coh_load(src + 0);
            aa += coh_load(src + 1);
            bb += coh_load(src + 2);
            bc += coh_load(src + 3);
        }
        const float na = fmaxf(sqrtf(aa), 1e-8f);
        const float nb = fmaxf(sqrtf(bb), 1e-8f);
        cos_acc += n / (na * nb);
        bce_acc += bc;
    }
    float wsv = (tid < NCH) ? coh_load(&wsum[tid]) : 0.f;

    #pragma unroll
    for (int off = 32; off >= 1; off >>= 1) {
        cos_acc += __shfl_down(cos_acc, off);
        bce_acc += __shfl_down(bce_acc, off);
        wsv     += __shfl_down(wsv, off);
    }
    __shared__ float s0[T1 / 64], s1[T1 / 64], s2[T1 / 64];
    if (lane == 0) { s0[wid] = cos_acc; s1[wid] = bce_acc; s2[wid] = wsv; }
    __syncthreads();
    if (tid == 0) {
        float cs = 0.f, bs = 0.f, wss = 0.f;
        #pragma unroll
        for (int i = 0; i < T1 / 64; ++i) { cs += s0[i]; bs += s1[i]; wss += s2[i]; }
        const float cosine_loss = -(cs / (float)B_ROWS);
        const float sub_graph   = bs / (wss + 1e-10f);
        out[0] = cosine_loss + sub_graph / 10.0f;
    }
}

extern "C" void kernel_launch(void* const* d_in, const int* in_sizes, int n_in,
                              void* d_out, int out_size, void* d_ws, size_t ws_size,
                              hipStream_t stream) {
    const float* pred = (const float*)d_in[0];   // prediction (B, C)
    const float* tgt  = (const float*)d_in[1];   // target     (B, C)
    const float* cw   = (const float*)d_in[2];   // cos_weights (C,)
    const float* bw   = (const float*)d_in[3];   // bce_weights (C,)
    float* out = (float*)d_out;

    char* ws = (char*)d_ws;
    float*        part    = (float*)ws;
    float*        wsum    = (float*)(ws + WS_WSUM_OFF);
    unsigned int* counter = (unsigned int*)(ws + WS_CTR_OFF);

    // Zero the arrival counter every launch (graph-legal memset node).
    hipMemsetAsync(counter, 0, sizeof(unsigned int), stream);

    coscel_fused<<<NBLK, T1, 0, stream>>>(pred, tgt, cw, bw, part, wsum, counter, out);
}

// Round 7
// 50.554 us; speedup vs baseline: 3.9996x; 1.5051x over previous
//
#include <hip/hip_runtime.h>

// Problem constants (fixed by the reference)
#define B_ROWS   512
#define C_COLS   65536
#define BR       4                    // rows per block
#define CCH      4096                 // columns per chunk
#define NCH      (C_COLS / CCH)       // 16 chunks per row
#define RG       (B_ROWS / BR)        // 128 row-groups
#define T1       256                  // threads, kernel 1
#define ITERS    (CCH / 4 / T1)       // 4 float4 per thread per stream
#define T2       512                  // threads, kernel 2 (== B_ROWS)

// ws layout: [0 .. B_ROWS*NCH) float4 row-chunk partials {num,a2,b2,bce}
//            then NCH floats: per-chunk sum of bce_weights
#define WS_F4_COUNT (B_ROWS * NCH)

__device__ __forceinline__ void wave_reduce4(float& a, float& b, float& c, float& d) {
    #pragma unroll
    for (int off = 32; off >= 1; off >>= 1) {
        a += __shfl_down(a, off);
        b += __shfl_down(b, off);
        c += __shfl_down(c, off);
        d += __shfl_down(d, off);
    }
}

// Kernel 1: each block = 4 rows x one 4096-col chunk.
// Weights loaded once per block serve all 4 rows.
// 52 VGPR / 34% occupancy verified optimal (rounds 2-6: every deviation
// broke a resource: prefetch -> VGPR cliff, bounds -> spills, fusion -> fences).
__global__ __launch_bounds__(T1) void coscel_partial(
    const float* __restrict__ pred,
    const float* __restrict__ tgt,
    const float* __restrict__ cw,
    const float* __restrict__ bw,
    float4* __restrict__ ws)
{
    const int blk  = blockIdx.x;          // 0 .. RG*NCH-1 (2048)
    const int rowg = blk / NCH;
    const int ch   = blk % NCH;
    const int tid  = threadIdx.x;

    const int row0 = rowg * BR;
    const size_t cbase = (size_t)ch * CCH;

    const float4* __restrict__ w4 = (const float4*)(cw + cbase);
    const float4* __restrict__ g4 = (const float4*)(bw + cbase);
    const float4* p4[BR];
    const float4* t4[BR];
    #pragma unroll
    for (int r = 0; r < BR; ++r) {
        p4[r] = (const float4*)(pred + (size_t)(row0 + r) * C_COLS + cbase);
        t4[r] = (const float4*)(tgt  + (size_t)(row0 + r) * C_COLS + cbase);
    }

    float num[BR], a2[BR], b2[BR], bce[BR];
    #pragma unroll
    for (int r = 0; r < BR; ++r) { num[r] = a2[r] = b2[r] = bce[r] = 0.f; }
    float gsum = 0.f;

    #pragma unroll 2
    for (int i = 0; i < ITERS; ++i) {
        const int idx = i * T1 + tid;     // coalesced
        const float4 w = w4[idx];
        const float4 g = g4[idx];
        gsum += g.x + g.y + g.z + g.w;

        float4 pv[BR], tv[BR];
        #pragma unroll
        for (int r = 0; r < BR; ++r) { pv[r] = p4[r][idx]; tv[r] = t4[r][idx]; }

        const float4 w2 = make_float4(w.x * w.x, w.y * w.y, w.z * w.z, w.w * w.w);

        #pragma unroll
        for (int r = 0; r < BR; ++r) {
            #define DO_COMP(comp)                                            \
            {                                                                \
                const float x  = tv[r].comp, y = pv[r].comp;                 \
                const float xy = x * y;                                      \
                num[r] = fmaf(xy,    w2.comp, num[r]);                       \
                a2[r]  = fmaf(x * x, w2.comp, a2[r]);                        \
                b2[r]  = fmaf(y * y, w2.comp, b2[r]);                        \
                const float e = __expf(-fabsf(x));                           \
                const float l = __logf(1.0f + e);                            \
                bce[r] += g.comp * (fmaxf(x, 0.0f) - xy + l);                \
            }
            DO_COMP(x) DO_COMP(y) DO_COMP(z) DO_COMP(w)
            #undef DO_COMP
        }
    }

    // Reduce each row's 4 values across the wave, plus gsum.
    #pragma unroll
    for (int r = 0; r < BR; ++r) wave_reduce4(num[r], a2[r], b2[r], bce[r]);
    #pragma unroll
    for (int off = 32; off >= 1; off >>= 1) gsum += __shfl_down(gsum, off);

    __shared__ float4 sred[T1 / 64][BR];
    __shared__ float  sg[T1 / 64];
    const int lane = tid & 63, wid = tid >> 6;
    if (lane == 0) {
        #pragma unroll
        for (int r = 0; r < BR; ++r) sred[wid][r] = make_float4(num[r], a2[r], b2[r], bce[r]);
        sg[wid] = gsum;
    }
    __syncthreads();
    if (tid == 0) {
        #pragma unroll
        for (int r = 0; r < BR; ++r) {
            float4 acc = sred[0][r];
            #pragma unroll
            for (int w_ = 1; w_ < T1 / 64; ++w_) {
                const float4 s = sred[w_][r];
                acc.x += s.x; acc.y += s.y; acc.z += s.z; acc.w += s.w;
            }
            ws[(size_t)(row0 + r) * NCH + ch] = acc;
        }
        if (rowg == 0) {
            float gs = sg[0] + sg[1] + sg[2] + sg[3];
            ((float*)(ws + WS_F4_COUNT))[ch] = gs;
        }
    }
}

// Kernel 2: fold chunk partials per row, cosine per row, global sums, final scalar.
__global__ __launch_bounds__(T2) void coscel_final(
    const float4* __restrict__ ws,
    float* __restrict__ out)
{
    const int tid = threadIdx.x;    // == row

    float num = 0.f, a2 = 0.f, b2 = 0.f, bce = 0.f;
    #pragma unroll
    for (int c = 0; c < NCH; ++c) {
        const float4 v = ws[(size_t)tid * NCH + c];
        num += v.x; a2 += v.y; b2 += v.z; bce += v.w;
    }
    const float na = fmaxf(sqrtf(a2), 1e-8f);
    const float nb = fmaxf(sqrtf(b2), 1e-8f);
    float cosv = num / (na * nb);

    const float* wpart = (const float*)(ws + WS_F4_COUNT);
    float wsum = (tid < NCH) ? wpart[tid] : 0.f;

    #pragma unroll
    for (int off = 32; off >= 1; off >>= 1) {
        cosv += __shfl_down(cosv, off);
        bce  += __shfl_down(bce,  off);
        wsum += __shfl_down(wsum, off);
    }
    __shared__ float s0[T2 / 64], s1[T2 / 64], s2[T2 / 64];
    const int lane = tid & 63, wid = tid >> 6;
    if (lane == 0) { s0[wid] = cosv; s1[wid] = bce; s2[wid] = wsum; }
    __syncthreads();
    if (tid == 0) {
        float cs = 0.f, bs = 0.f, wss = 0.f;
        #pragma unroll
        for (int i = 0; i < T2 / 64; ++i) { cs += s0[i]; bs += s1[i]; wss += s2[i]; }
        const float cosine_loss = -(cs / (float)B_ROWS);
        const float sub_graph   = bs / (wss + 1e-10f);
        out[0] = cosine_loss + sub_graph / 10.0f;
    }
}

extern "C" void kernel_launch(void* const* d_in, const int* in_sizes, int n_in,
                              void* d_out, int out_size, void* d_ws, size_t ws_size,
                              hipStream_t stream) {
    const float* pred = (const float*)d_in[0];   // prediction (B, C)
    const float* tgt  = (const float*)d_in[1];   // target     (B, C)
    const float* cw   = (const float*)d_in[2];   // cos_weights (C,)
    const float* bw   = (const float*)d_in[3];   // bce_weights (C,)
    float* out = (float*)d_out;
    float4* ws = (float4*)d_ws;                  // 128 KiB partials + 64 B wsum

    coscel_partial<<<RG * NCH, T1, 0, stream>>>(pred, tgt, cw, bw, ws);
    coscel_final<<<1, T2, 0, stream>>>(ws, out);
}